// Round 2
// baseline (3639.970 us; speedup 1.0000x reference)
//
#include <hip/hip_runtime.h>
#include <hip/hip_bf16.h>
#include <cstddef>

// Problem constants
#define HW      512
#define CCH     16           // channels
#define KB11    11           // spline bases per channel
#define TILE    32           // output tile (32x32)
#define HALO    34           // input tile with 1-pixel halo
#define PSTR    12           // floats per pixel in LDS derived tile

// Derived values for one input value v:
//   d[0]    = silu(v)
//   d[1+k]  = cubic B-spline basis k (k=0..10) on grid g(i) = -1.75 + 0.25*i
__device__ __forceinline__ void compute_derived(float x, float* d) {
    d[0] = x / (1.0f + __expf(-x));           // silu
    float b0[14];
#pragma unroll
    for (int i = 0; i < 14; ++i) {
        float gl = -1.75f + 0.25f * i;
        float gr = gl + 0.25f;
        b0[i] = (x >= gl && x < gr) ? 1.0f : 0.0f;
    }
    float b1[13];
#pragma unroll
    for (int i = 0; i < 13; ++i) {
        float gi = -1.75f + 0.25f * i;
        b1[i] = (x - gi) * 4.0f * b0[i] + ((gi + 0.50f) - x) * 4.0f * b0[i + 1];
    }
    float b2[12];
#pragma unroll
    for (int i = 0; i < 12; ++i) {
        float gi = -1.75f + 0.25f * i;
        b2[i] = (x - gi) * 2.0f * b1[i] + ((gi + 0.75f) - x) * 2.0f * b1[i + 1];
    }
#pragma unroll
    for (int i = 0; i < 11; ++i) {
        float gi = -1.75f + 0.25f * i;
        d[1 + i] = (x - gi) * (4.0f / 3.0f) * b2[i]
                 + ((gi + 1.00f) - x) * (4.0f / 3.0f) * b2[i + 1];
    }
}

// Fused KAN conv layer (pre-norm output), plain input (transform pre-applied):
//   z[b,co,y,x] = sum_{ci,dy,dx,k} derived_k(in[b,ci,y+dy-1,x+dx-1]) * W[co,ci,k,dy,dx]
// bw: (16,16,3,3)  sw: (16,176,3,3)
__global__ __launch_bounds__(256, 2) void conv_kan(
    const float* __restrict__ in,
    const float* __restrict__ bw,
    const float* __restrict__ sw,
    float* __restrict__ z)
{
    __shared__ float dtile[HALO * HALO * PSTR];   // 55488 B
    __shared__ float wtile[9 * 12 * 16];          // 6912 B   [tap][k][co]

    const int tid = threadIdx.x;
    const int tx = tid & 15;
    const int ty = tid >> 4;
    const int bx0 = blockIdx.x * TILE;
    const int by0 = blockIdx.y * TILE;
    const int b = blockIdx.z;

    float acc[4][16];
#pragma unroll
    for (int p = 0; p < 4; ++p)
#pragma unroll
        for (int c = 0; c < 16; ++c) acc[p][c] = 0.0f;

#pragma unroll 1
    for (int cin = 0; cin < CCH; ++cin) {
        __syncthreads();
        // ---- stage weights for this cin: wtile[tap][k][co] ----
        for (int e = tid; e < 1728; e += 256) {
            int tap = e / 192;
            int r = e - tap * 192;
            int k = r >> 4;
            int co = r & 15;
            float w = (k == 0) ? bw[(co * CCH + cin) * 9 + tap]
                               : sw[((size_t)co * (CCH * KB11) + cin * KB11 + (k - 1)) * 9 + tap];
            wtile[e] = w;
        }
        // ---- stage derived values for this input channel into LDS ----
        for (int idx = tid; idx < HALO * HALO; idx += 256) {
            int iy = idx / HALO;
            int ix = idx - iy * HALO;
            int gy = by0 + iy - 1;
            int gx = bx0 + ix - 1;
            float4 d0 = {0.f, 0.f, 0.f, 0.f};
            float4 d1 = {0.f, 0.f, 0.f, 0.f};
            float4 d2 = {0.f, 0.f, 0.f, 0.f};
            if ((unsigned)gy < (unsigned)HW && (unsigned)gx < (unsigned)HW) {
                float v = in[(((size_t)b * CCH + cin) << 18) + ((size_t)gy << 9) + gx];
                float d[12];
                compute_derived(v, d);
                d0 = make_float4(d[0], d[1], d[2], d[3]);
                d1 = make_float4(d[4], d[5], d[6], d[7]);
                d2 = make_float4(d[8], d[9], d[10], d[11]);
            }
            float* p = &dtile[idx * PSTR];
            *reinterpret_cast<float4*>(p)     = d0;
            *reinterpret_cast<float4*>(p + 4) = d1;
            *reinterpret_cast<float4*>(p + 8) = d2;
        }
        __syncthreads();

        // ---- accumulate: 4 pixels x 16 couts per thread ----
#pragma unroll 1
        for (int tap = 0; tap < 9; ++tap) {
            const int tdy = tap / 3;
            const int tdx = tap - tdy * 3;
            float v[4][12];
#pragma unroll
            for (int p = 0; p < 4; ++p) {
                int py = ty + ((p >> 1) << 4) + tdy;
                int px = tx + ((p & 1) << 4) + tdx;
                const float* s = &dtile[(py * HALO + px) * PSTR];
                float4 t0 = *reinterpret_cast<const float4*>(s);
                float4 t1 = *reinterpret_cast<const float4*>(s + 4);
                float4 t2 = *reinterpret_cast<const float4*>(s + 8);
                v[p][0] = t0.x; v[p][1] = t0.y; v[p][2]  = t0.z; v[p][3]  = t0.w;
                v[p][4] = t1.x; v[p][5] = t1.y; v[p][6]  = t1.z; v[p][7]  = t1.w;
                v[p][8] = t2.x; v[p][9] = t2.y; v[p][10] = t2.z; v[p][11] = t2.w;
            }
            const float* wp = &wtile[tap * 192];
#pragma unroll 4
            for (int k = 0; k < 12; ++k) {
                float4 w0 = *reinterpret_cast<const float4*>(&wp[k * 16 + 0]);
                float4 w1 = *reinterpret_cast<const float4*>(&wp[k * 16 + 4]);
                float4 w2 = *reinterpret_cast<const float4*>(&wp[k * 16 + 8]);
                float4 w3 = *reinterpret_cast<const float4*>(&wp[k * 16 + 12]);
#pragma unroll
                for (int p = 0; p < 4; ++p) {
                    float vv = v[p][k];
                    acc[p][0]  = fmaf(w0.x, vv, acc[p][0]);
                    acc[p][1]  = fmaf(w0.y, vv, acc[p][1]);
                    acc[p][2]  = fmaf(w0.z, vv, acc[p][2]);
                    acc[p][3]  = fmaf(w0.w, vv, acc[p][3]);
                    acc[p][4]  = fmaf(w1.x, vv, acc[p][4]);
                    acc[p][5]  = fmaf(w1.y, vv, acc[p][5]);
                    acc[p][6]  = fmaf(w1.z, vv, acc[p][6]);
                    acc[p][7]  = fmaf(w1.w, vv, acc[p][7]);
                    acc[p][8]  = fmaf(w2.x, vv, acc[p][8]);
                    acc[p][9]  = fmaf(w2.y, vv, acc[p][9]);
                    acc[p][10] = fmaf(w2.z, vv, acc[p][10]);
                    acc[p][11] = fmaf(w2.w, vv, acc[p][11]);
                    acc[p][12] = fmaf(w3.x, vv, acc[p][12]);
                    acc[p][13] = fmaf(w3.y, vv, acc[p][13]);
                    acc[p][14] = fmaf(w3.z, vv, acc[p][14]);
                    acc[p][15] = fmaf(w3.w, vv, acc[p][15]);
                }
            }
        }
    }

    // ---- write pre-norm z ----
#pragma unroll
    for (int p = 0; p < 4; ++p) {
        int gy = by0 + ty + ((p >> 1) << 4);
        int gx = bx0 + tx + ((p & 1) << 4);
#pragma unroll
        for (int co = 0; co < 16; ++co) {
            z[(((size_t)b * CCH + co) << 18) + ((size_t)gy << 9) + gx] = acc[p][co];
        }
    }
}

// Stage 1 of instance-norm reduction: per (bc, chunk) partial sum / sumsq.
// grid = (64 chunks, 64 bc), block = 256. Each block reduces 4096 elements.
__global__ void __launch_bounds__(256) reduce_partial(
    const float* __restrict__ z, float* __restrict__ part)
{
    const int bc = blockIdx.y;
    const float* p = z + ((size_t)bc << 18) + ((size_t)blockIdx.x << 12);
    float s = 0.0f, q = 0.0f;
    for (int i = threadIdx.x; i < 4096; i += 256) {
        float v = p[i];
        s += v;
        q = fmaf(v, v, q);
    }
#pragma unroll
    for (int off = 32; off > 0; off >>= 1) {
        s += __shfl_down(s, off);
        q += __shfl_down(q, off);
    }
    __shared__ float ls[4], lq[4];
    const int wid = threadIdx.x >> 6;
    if ((threadIdx.x & 63) == 0) { ls[wid] = s; lq[wid] = q; }
    __syncthreads();
    if (threadIdx.x == 0) {
        float S = ls[0] + ls[1] + ls[2] + ls[3];
        float Q = lq[0] + lq[1] + lq[2] + lq[3];
        part[((size_t)bc * 64 + blockIdx.x) * 2]     = S;
        part[((size_t)bc * 64 + blockIdx.x) * 2 + 1] = Q;
    }
}

// Stage 2: fold 64 partials per bc into (mean, rstd). 1 block of 64 threads.
__global__ void reduce_final(const float* __restrict__ part, float* __restrict__ stats)
{
    const int bc = threadIdx.x;   // 0..63
    float s = 0.0f, q = 0.0f;
    for (int i = 0; i < 64; ++i) {
        s += part[((size_t)bc * 64 + i) * 2];
        q += part[((size_t)bc * 64 + i) * 2 + 1];
    }
    const float inv = 1.0f / 262144.0f;
    float m = s * inv;
    float var = q * inv - m * m;
    stats[bc * 2]     = m;
    stats[bc * 2 + 1] = rsqrtf(var + 1e-5f);
}

// y = prelu(instancenorm(z)) in place, float4-wide. 16384 blocks x 256.
__global__ void __launch_bounds__(256) norm_prelu(
    float* __restrict__ y, const float* __restrict__ stats,
    const float* __restrict__ a_ptr)
{
    const float a = *a_ptr;
    const int i4 = blockIdx.x * 256 + threadIdx.x;
    const int bc = i4 >> 16;
    const float m = stats[bc * 2];
    const float r = stats[bc * 2 + 1];
    float4 v = reinterpret_cast<float4*>(y)[i4];
    float t;
    t = (v.x - m) * r; v.x = (t >= 0.f) ? t : a * t;
    t = (v.y - m) * r; v.y = (t >= 0.f) ? t : a * t;
    t = (v.z - m) * r; v.z = (t >= 0.f) ? t : a * t;
    t = (v.w - m) * r; v.w = (t >= 0.f) ? t : a * t;
    reinterpret_cast<float4*>(y)[i4] = v;
}

// Final: out = sigmoid(prelu(instancenorm(z2))) in place on d_out, float4-wide.
__global__ void __launch_bounds__(256) final_sigmoid(
    float* __restrict__ out, const float* __restrict__ stats,
    const float* __restrict__ a_ptr)
{
    const float a = *a_ptr;
    const int i4 = blockIdx.x * 256 + threadIdx.x;
    const int bc = i4 >> 16;
    const float m = stats[bc * 2];
    const float r = stats[bc * 2 + 1];
    float4 v = reinterpret_cast<float4*>(out)[i4];
    float t;
    t = (v.x - m) * r; t = (t >= 0.f) ? t : a * t; v.x = 1.0f / (1.0f + __expf(-t));
    t = (v.y - m) * r; t = (t >= 0.f) ? t : a * t; v.y = 1.0f / (1.0f + __expf(-t));
    t = (v.z - m) * r; t = (t >= 0.f) ? t : a * t; v.z = 1.0f / (1.0f + __expf(-t));
    t = (v.w - m) * r; t = (t >= 0.f) ? t : a * t; v.w = 1.0f / (1.0f + __expf(-t));
    reinterpret_cast<float4*>(out)[i4] = v;
}

extern "C" void kernel_launch(void* const* d_in, const int* in_sizes, int n_in,
                              void* d_out, int out_size, void* d_ws, size_t ws_size,
                              hipStream_t stream)
{
    const float* x        = (const float*)d_in[0];
    const float* base_w1  = (const float*)d_in[1];
    const float* spline_w1= (const float*)d_in[2];
    const float* prelu_a1 = (const float*)d_in[3];
    const float* base_w2  = (const float*)d_in[4];
    const float* spline_w2= (const float*)d_in[5];
    const float* prelu_a2 = (const float*)d_in[6];
    float* out_f = (float*)d_out;
    float* ws_f  = (float*)d_ws;

    // Buffer plan — NOTHING outside ws[0,64MiB) and d_out[0,64MiB):
    //   z1/y1   : ws_f[0 .. 16.78M)                (64 MiB)
    //   part1   : out_f[0 .. 8192)                 (d_out free until conv2)
    //   stats1  : out_f[8192 .. 8320)
    //   z2      : out_f[0 .. 16.78M)               (overwrites dead part1/stats1)
    //   part2   : ws_f[0 .. 8192)                  (y1 dead after conv2)
    //   stats2  : ws_f[8192 .. 8320)
    float* z1     = ws_f;
    float* part1  = out_f;
    float* stats1 = out_f + 8192;
    float* part2  = ws_f;
    float* stats2 = ws_f + 8192;

    dim3 cgrid(HW / TILE, HW / TILE, 4);   // (16,16,4)
    dim3 cblk(256);
    dim3 rgrid(64, 64);
    dim3 egrid(16384);                     // elementwise float4 grid

    // ---- layer 1 ----
    conv_kan<<<cgrid, cblk, 0, stream>>>(x, base_w1, spline_w1, z1);
    reduce_partial<<<rgrid, cblk, 0, stream>>>(z1, part1);
    reduce_final<<<1, 64, 0, stream>>>(part1, stats1);
    norm_prelu<<<egrid, cblk, 0, stream>>>(z1, stats1, prelu_a1);   // z1 -> y1 in place

    // ---- layer 2 ----
    conv_kan<<<cgrid, cblk, 0, stream>>>(z1, base_w2, spline_w2, out_f);  // z2 -> d_out
    reduce_partial<<<rgrid, cblk, 0, stream>>>(out_f, part2);
    reduce_final<<<1, 64, 0, stream>>>(part2, stats2);

    // ---- final: norm + prelu + sigmoid, in place on d_out ----
    final_sigmoid<<<egrid, cblk, 0, stream>>>(out_f, stats2, prelu_a2);
}